// Round 13
// baseline (175.184 us; speedup 1.0000x reference)
//
#include <hip/hip_runtime.h>
#include <hip/hip_bf16.h>

// Problem constants (AttentionalPlanarRemapping): N=32, C=64, H=W=128, E=512
#define NB   32
#define CC   64
#define HW   16384          // 128*128
#define EE   512
#define CC2  4096           // C*C

// ---------------------------------------------------------------------------
// Kernel 1: logits[n][j] = dot(atts[n,:], W[j,:]) + b[j]   (unchanged)
// ---------------------------------------------------------------------------
__global__ __launch_bounds__(256) void logits_kernel(
    const float* __restrict__ atts, const float* __restrict__ W,
    const float* __restrict__ b, float* __restrict__ logits) {
    const int t  = threadIdx.x;
    const int j  = blockIdx.x * 2 + (t & 1);
    const int n  = (t >> 1) & 31;
    const int kq = t >> 6;                 // 0..3
    const float* __restrict__ wrow = W + (size_t)j * EE + kq * 128;
    const float* __restrict__ arow = atts + (size_t)n * EE + kq * 128;
    float acc0 = 0.f, acc1 = 0.f;
    #pragma unroll
    for (int k = 0; k < 128; k += 8) {
        float4 w0 = *reinterpret_cast<const float4*>(wrow + k);
        float4 a0 = *reinterpret_cast<const float4*>(arow + k);
        float4 w1 = *reinterpret_cast<const float4*>(wrow + k + 4);
        float4 a1 = *reinterpret_cast<const float4*>(arow + k + 4);
        acc0 = fmaf(w0.x, a0.x, acc0); acc0 = fmaf(w0.y, a0.y, acc0);
        acc0 = fmaf(w0.z, a0.z, acc0); acc0 = fmaf(w0.w, a0.w, acc0);
        acc1 = fmaf(w1.x, a1.x, acc1); acc1 = fmaf(w1.y, a1.y, acc1);
        acc1 = fmaf(w1.z, a1.z, acc1); acc1 = fmaf(w1.w, a1.w, acc1);
    }
    __shared__ float part[256];
    part[t] = acc0 + acc1;
    __syncthreads();
    if (t < 64) {
        const int jj = blockIdx.x * 2 + (t & 1);
        const int nn = t >> 1;
        const float r = part[t] + part[t + 64] + part[t + 128] + part[t + 192];
        logits[(size_t)nn * CC2 + jj] = r + b[jj];
    }
}

// ---------------------------------------------------------------------------
// Kernel 2: double softmax. One block per n. Output TRANSPOSED fp32:
//   aT[n][d][c] = a[n][c][d]   (d-major so einsum reads a[d][c0..c0+7] runs)
// ---------------------------------------------------------------------------
__global__ __launch_bounds__(256) void softmax_kernel(
    const float* __restrict__ logits, float* __restrict__ aT) {
    const int n = blockIdx.x;
    const int t = threadIdx.x;
    __shared__ float s[CC2];
    __shared__ float wmax[4];
    __shared__ float wsum[4];

    const float* __restrict__ L = logits + (size_t)n * CC2;

    float lmax = -1e30f;
    for (int i = t; i < CC2; i += 256) {
        float v = L[i];
        s[i] = v;
        lmax = fmaxf(lmax, v);
    }
    #pragma unroll
    for (int off = 32; off > 0; off >>= 1) lmax = fmaxf(lmax, __shfl_xor(lmax, off));
    if ((t & 63) == 0) wmax[t >> 6] = lmax;
    __syncthreads();
    const float bmax = fmaxf(fmaxf(wmax[0], wmax[1]), fmaxf(wmax[2], wmax[3]));

    float lsum = 0.f;
    for (int i = t; i < CC2; i += 256) {
        float e = __expf(s[i] - bmax);
        s[i] = e;
        lsum += e;
    }
    #pragma unroll
    for (int off = 32; off > 0; off >>= 1) lsum += __shfl_xor(lsum, off);
    if ((t & 63) == 0) wsum[t >> 6] = lsum;
    __syncthreads();
    const float inv = 1.f / (wsum[0] + wsum[1] + wsum[2] + wsum[3]);

    for (int i = t; i < CC2; i += 256) s[i] *= inv;
    __syncthreads();

    // second softmax: 4 threads per row c, each covering 16 d's
    const int c = t >> 2;          // 0..63
    const int q = t & 3;           // 0..3
    const float* __restrict__ row = s + c * CC + q * 16;
    float mx = -1e30f;
    #pragma unroll
    for (int i = 0; i < 16; ++i) mx = fmaxf(mx, row[i]);
    mx = fmaxf(mx, __shfl_xor(mx, 1));
    mx = fmaxf(mx, __shfl_xor(mx, 2));
    float sum = 0.f;
    #pragma unroll
    for (int i = 0; i < 16; ++i) sum += __expf(row[i] - mx);
    sum += __shfl_xor(sum, 1);
    sum += __shfl_xor(sum, 2);
    const float isum = 1.f / sum;
    float* __restrict__ dst = aT + (size_t)n * CC2 + c;   // aT[n][d][c]
    #pragma unroll
    for (int i = 0; i < 16; ++i) dst[(q * 16 + i) * CC] = __expf(row[i] - mx) * isum;
}

// ---------------------------------------------------------------------------
// Kernel 3 (fp32 VALU, LINEAR STREAMS + XCD-co-located L2 reuse):
//   out[n,c,px] = sum_d a[n,c,d] * img[n,d,px]
// grid 2048 blocks x 256 thr. bid = cg*256 + n*8 + pxt  (cg 0..7, n 0..31,
// pxt 0..7): the 8 cg-blocks sharing (n,pxt) have equal bid%8 -> same XCD
// under round-robin dispatch -> img[n] tile is read from HBM once and served
// 7x from that XCD's L2 (4 MB = exactly one n-slice).
// Block reads img[n][d][pxt*2048 .. +2047] sequentially in d: every wave-
// instr is 1 KB contiguous; writes 8 output rows as linear 8-KB runs.
// Thread: acc[8c][2x float4 px] = 64 VGPR accs; per d: 2 global float4
// loads + 2 wave-uniform ds_read_b128 (a values) + 64 FMA.
// __launch_bounds__(256,2): 256-reg budget -> accs stay in arch VGPRs
// (no AGPR moves, no spill — the R2/R3/R4 failure). No barriers in loop.
// ---------------------------------------------------------------------------
__global__ __launch_bounds__(256, 2) void einsum_kernel(
    const float* __restrict__ img, const float* __restrict__ aT,
    float* __restrict__ out) {
    const int t   = threadIdx.x;
    const int bid = blockIdx.x;
    const int cg  = bid >> 8;                  // 0..7
    const int n   = (bid >> 3) & 31;           // 0..31
    const int pxt = bid & 7;                   // 0..7
    const int c0  = cg * 8;
    const int px0 = pxt * 2048;

    // a-slice: sA[d][i] = a[n][c0+i][d], 2 KB
    __shared__ __align__(16) float sA[CC][8];
    for (int i = t; i < CC * 8; i += 256)
        sA[i >> 3][i & 7] = aT[(size_t)n * CC2 + (i >> 3) * CC + c0 + (i & 7)];
    __syncthreads();

    float acc[8][8];
    #pragma unroll
    for (int c = 0; c < 8; ++c)
        #pragma unroll
        for (int p = 0; p < 8; ++p) acc[c][p] = 0.f;

    const float* __restrict__ ip = img + (size_t)n * (CC * HW) + px0 + t * 4;

    #pragma unroll 4
    for (int d = 0; d < CC; ++d) {
        const float4 u0 = *reinterpret_cast<const float4*>(ip + (size_t)d * HW);
        const float4 u1 = *reinterpret_cast<const float4*>(ip + (size_t)d * HW + 1024);
        const float4 a0 = *reinterpret_cast<const float4*>(&sA[d][0]);
        const float4 a1 = *reinterpret_cast<const float4*>(&sA[d][4]);
        const float av[8] = {a0.x, a0.y, a0.z, a0.w, a1.x, a1.y, a1.z, a1.w};
        #pragma unroll
        for (int c = 0; c < 8; ++c) {
            acc[c][0] = fmaf(av[c], u0.x, acc[c][0]);
            acc[c][1] = fmaf(av[c], u0.y, acc[c][1]);
            acc[c][2] = fmaf(av[c], u0.z, acc[c][2]);
            acc[c][3] = fmaf(av[c], u0.w, acc[c][3]);
            acc[c][4] = fmaf(av[c], u1.x, acc[c][4]);
            acc[c][5] = fmaf(av[c], u1.y, acc[c][5]);
            acc[c][6] = fmaf(av[c], u1.z, acc[c][6]);
            acc[c][7] = fmaf(av[c], u1.w, acc[c][7]);
        }
    }

    float* __restrict__ op = out + (size_t)n * (CC * HW) + (size_t)c0 * HW + px0 + t * 4;
    #pragma unroll
    for (int c = 0; c < 8; ++c) {
        float4 r0, r1;
        r0.x = acc[c][0]; r0.y = acc[c][1]; r0.z = acc[c][2]; r0.w = acc[c][3];
        r1.x = acc[c][4]; r1.y = acc[c][5]; r1.z = acc[c][6]; r1.w = acc[c][7];
        *reinterpret_cast<float4*>(op + (size_t)c * HW)        = r0;
        *reinterpret_cast<float4*>(op + (size_t)c * HW + 1024) = r1;
    }
}

// ---------------------------------------------------------------------------
extern "C" void kernel_launch(void* const* d_in, const int* in_sizes, int n_in,
                              void* d_out, int out_size, void* d_ws, size_t ws_size,
                              hipStream_t stream) {
    const float* images = (const float*)d_in[0];   // [32,64,128,128]
    const float* atts   = (const float*)d_in[1];   // [32,512]
    const float* W      = (const float*)d_in[2];   // [4096,512]
    const float* b      = (const float*)d_in[3];   // [4096]
    float* out = (float*)d_out;                    // [32,64,128,128]

    // workspace: logits f32 [32*4096] + aT f32 [32*4096]  (1 MiB total)
    float* logits = (float*)d_ws;
    float* aT     = logits + NB * CC2;

    logits_kernel<<<CC2 / 2, 256, 0, stream>>>(atts, W, b, logits);
    softmax_kernel<<<NB, 256, 0, stream>>>(logits, aT);
    einsum_kernel<<<2048, 256, 0, stream>>>(images, aT, out);
}

// Round 14
// 89.240 us; speedup vs baseline: 1.9631x; 1.9631x over previous
//
#include <hip/hip_runtime.h>
#include <hip/hip_bf16.h>

// Problem constants (AttentionalPlanarRemapping): N=32, C=64, H=W=128, E=512
#define NB   32
#define CC   64
#define HW   16384          // 128*128
#define EE   512
#define CC2  4096           // C*C

using short8  = __attribute__((ext_vector_type(8))) short;
using f32x16  = __attribute__((ext_vector_type(16))) float;

// fp32 -> bf16 round-to-nearest-even
__device__ __forceinline__ unsigned short f2bf(float x) {
    unsigned int u = __float_as_uint(x);
    u += 0x7FFFu + ((u >> 16) & 1u);
    return (unsigned short)(u >> 16);
}

// ---------------------------------------------------------------------------
// Kernel 1: logits[n][j] = dot(atts[n,:], W[j,:]) + b[j]   (unchanged)
// ---------------------------------------------------------------------------
__global__ __launch_bounds__(256) void logits_kernel(
    const float* __restrict__ atts, const float* __restrict__ W,
    const float* __restrict__ b, float* __restrict__ logits) {
    const int t  = threadIdx.x;
    const int j  = blockIdx.x * 2 + (t & 1);
    const int n  = (t >> 1) & 31;
    const int kq = t >> 6;                 // 0..3
    const float* __restrict__ wrow = W + (size_t)j * EE + kq * 128;
    const float* __restrict__ arow = atts + (size_t)n * EE + kq * 128;
    float acc0 = 0.f, acc1 = 0.f;
    #pragma unroll
    for (int k = 0; k < 128; k += 8) {
        float4 w0 = *reinterpret_cast<const float4*>(wrow + k);
        float4 a0 = *reinterpret_cast<const float4*>(arow + k);
        float4 w1 = *reinterpret_cast<const float4*>(wrow + k + 4);
        float4 a1 = *reinterpret_cast<const float4*>(arow + k + 4);
        acc0 = fmaf(w0.x, a0.x, acc0); acc0 = fmaf(w0.y, a0.y, acc0);
        acc0 = fmaf(w0.z, a0.z, acc0); acc0 = fmaf(w0.w, a0.w, acc0);
        acc1 = fmaf(w1.x, a1.x, acc1); acc1 = fmaf(w1.y, a1.y, acc1);
        acc1 = fmaf(w1.z, a1.z, acc1); acc1 = fmaf(w1.w, a1.w, acc1);
    }
    __shared__ float part[256];
    part[t] = acc0 + acc1;
    __syncthreads();
    if (t < 64) {
        const int jj = blockIdx.x * 2 + (t & 1);
        const int nn = t >> 1;
        const float r = part[t] + part[t + 64] + part[t + 128] + part[t + 192];
        logits[(size_t)nn * CC2 + jj] = r + b[jj];
    }
}

// ---------------------------------------------------------------------------
// Kernel 2: double softmax, packed A output; 512 threads (halved serial
// chains vs 256-thr version). Second softmax: 8 threads per row c, 8 d's
// each (one 8-run lies fully within one (ks,lh) group -> single uint4 store).
//   a_pk[n][ks][half][l][e] = a[n][c=32*half+(l&31)][k=ks*16+(l>>5)*8+e]
// ---------------------------------------------------------------------------
__global__ __launch_bounds__(512) void softmax_kernel(
    const float* __restrict__ logits, unsigned short* __restrict__ a_pk) {
    const int n = blockIdx.x;
    const int t = threadIdx.x;
    __shared__ float s[CC2];
    __shared__ float wred[8];
    __shared__ float rowmx[CC];
    __shared__ float rowis[CC];

    const float* __restrict__ L = logits + (size_t)n * CC2;

    // ---- softmax-1 over 4096 ----
    float lmax = -1e30f;
    #pragma unroll
    for (int i = 0; i < 8; ++i) {
        const int idx = t + i * 512;
        float v = L[idx];
        s[idx] = v;
        lmax = fmaxf(lmax, v);
    }
    #pragma unroll
    for (int off = 32; off > 0; off >>= 1) lmax = fmaxf(lmax, __shfl_xor(lmax, off));
    if ((t & 63) == 0) wred[t >> 6] = lmax;
    __syncthreads();
    float bmax = wred[0];
    #pragma unroll
    for (int i = 1; i < 8; ++i) bmax = fmaxf(bmax, wred[i]);

    float lsum = 0.f;
    #pragma unroll
    for (int i = 0; i < 8; ++i) {
        const int idx = t + i * 512;
        float e = __expf(s[idx] - bmax);
        s[idx] = e;
        lsum += e;
    }
    #pragma unroll
    for (int off = 32; off > 0; off >>= 1) lsum += __shfl_xor(lsum, off);
    __syncthreads();               // all s[] writes done before re-use below
    if ((t & 63) == 0) wred[t >> 6] = lsum;
    __syncthreads();
    float bsum = wred[0];
    #pragma unroll
    for (int i = 1; i < 8; ++i) bsum += wred[i];
    const float inv = 1.f / bsum;

    // ---- softmax-2: 8 threads per row c, 8 d's each ----
    const int c  = t >> 3;         // 0..63
    const int q8 = (t & 7) * 8;    // d0 = 0,8,..,56
    const float* __restrict__ row = s + c * CC + q8;

    float v[8];
    #pragma unroll
    for (int i = 0; i < 8; ++i) v[i] = row[i] * inv;

    float mx = v[0];
    #pragma unroll
    for (int i = 1; i < 8; ++i) mx = fmaxf(mx, v[i]);
    mx = fmaxf(mx, __shfl_xor(mx, 1));
    mx = fmaxf(mx, __shfl_xor(mx, 2));
    mx = fmaxf(mx, __shfl_xor(mx, 4));
    float sum = 0.f;
    #pragma unroll
    for (int i = 0; i < 8; ++i) sum += __expf(v[i] - mx);
    sum += __shfl_xor(sum, 1);
    sum += __shfl_xor(sum, 2);
    sum += __shfl_xor(sum, 4);
    const float isum = 1.f / sum;

    union { uint4 u; unsigned short h[8]; } pk;
    #pragma unroll
    for (int i = 0; i < 8; ++i) pk.h[i] = f2bf(__expf(v[i] - mx) * isum);

    // dest: ks = q8>>4, lh = (q8>>3)&1, lane = lh*32 + (c&31), half = c>>5
    const int ks   = q8 >> 4;
    const int lh   = (q8 >> 3) & 1;
    const int half = c >> 5;
    unsigned short* __restrict__ dst =
        a_pk + (size_t)n * CC2 + (size_t)(ks * 2 + half) * 512
             + (lh * 32 + (c & 31)) * 8;
    *reinterpret_cast<uint4*>(dst) = pk.u;
}

// ---------------------------------------------------------------------------
// Kernel 3 (MFMA + LDS-staged B; R12-verbatim structure, 75.6 us measured)
// + bijective XCD swizzle (2048 blocks % 8 == 0): each XCD covers a
// contiguous 256-block (= 4 n-slices, 32 MB) region -> per-channel DRAM
// page locality on the read stream.
// grid 2048 x 512 thr (8 waves). Tile = [64 d][256 px].
// ---------------------------------------------------------------------------
__global__ __launch_bounds__(512) void einsum_kernel(
    const float* __restrict__ img, const unsigned short* __restrict__ a_pk,
    float* __restrict__ out) {
    const int t    = threadIdx.x;
    const int lane = t & 63;
    const int wv   = t >> 6;                   // wave 0..7
    // XCD swizzle: orig = (swz%8)*256 + swz/8
    const int swz  = blockIdx.x;
    const int bid  = (swz & 7) * 256 + (swz >> 3);
    const int n    = bid >> 6;                 // 0..31
    const int px0  = (bid & 63) * 256;
    const int lh   = lane >> 5;                // k-group half
    const int lc   = lane & 31;

    __shared__ unsigned short sImg[CC * 256];  // [d][px] bf16, 32 KB

    // ---- stage: 8 independent float4 loads, then cvt + b64 LDS writes ----
    {
        const int px_l = (t & 63) * 4;         // 0..252
        const int d0   = (t >> 6) * 8;         // 0,8,..,56
        const float* __restrict__ gp = img + (size_t)n * (CC * HW) + px0 + px_l;
        float4 v0 = *reinterpret_cast<const float4*>(gp + (size_t)(d0 + 0) * HW);
        float4 v1 = *reinterpret_cast<const float4*>(gp + (size_t)(d0 + 1) * HW);
        float4 v2 = *reinterpret_cast<const float4*>(gp + (size_t)(d0 + 2) * HW);
        float4 v3 = *reinterpret_cast<const float4*>(gp + (size_t)(d0 + 3) * HW);
        float4 v4 = *reinterpret_cast<const float4*>(gp + (size_t)(d0 + 4) * HW);
        float4 v5 = *reinterpret_cast<const float4*>(gp + (size_t)(d0 + 5) * HW);
        float4 v6 = *reinterpret_cast<const float4*>(gp + (size_t)(d0 + 6) * HW);
        float4 v7 = *reinterpret_cast<const float4*>(gp + (size_t)(d0 + 7) * HW);
        union { uint2 u; unsigned short h[4]; } pk;
        #define STG(i, vv) \
            pk.h[0] = f2bf(vv.x); pk.h[1] = f2bf(vv.y); \
            pk.h[2] = f2bf(vv.z); pk.h[3] = f2bf(vv.w); \
            *reinterpret_cast<uint2*>(&sImg[(d0 + i) * 256 + px_l]) = pk.u;
        STG(0, v0) STG(1, v1) STG(2, v2) STG(3, v3)
        STG(4, v4) STG(5, v5) STG(6, v6) STG(7, v7)
        #undef STG
    }
    __syncthreads();

    // ---- compute ----
    const int px_w = wv * 32 + lc;
    const unsigned short* __restrict__ apn = a_pk + (size_t)n * CC2;

    f32x16 acc0 = {};   // c = 0..31
    f32x16 acc1 = {};   // c = 32..63

    #pragma unroll
    for (int ks = 0; ks < 4; ++ks) {
        const int kbase = ks * 16 + lh * 8;
        union { short8 v; unsigned short h[8]; } bf;
        #pragma unroll
        for (int e = 0; e < 8; ++e)
            bf.h[e] = sImg[(kbase + e) * 256 + px_w];
        short8 a0 = *reinterpret_cast<const short8*>(apn + (ks * 2 + 0) * 512 + lane * 8);
        short8 a1 = *reinterpret_cast<const short8*>(apn + (ks * 2 + 1) * 512 + lane * 8);
        acc0 = __builtin_amdgcn_mfma_f32_32x32x16_bf16(a0, bf.v, acc0, 0, 0, 0);
        acc1 = __builtin_amdgcn_mfma_f32_32x32x16_bf16(a1, bf.v, acc1, 0, 0, 0);
    }

    float* __restrict__ op = out + (size_t)n * (CC * HW) + px0 + px_w;
    #pragma unroll
    for (int r = 0; r < 16; ++r) {
        const int row = (r & 3) + 8 * (r >> 2) + 4 * lh;
        op[(size_t)row * HW]        = acc0[r];
        op[(size_t)(row + 32) * HW] = acc1[r];
    }
}

// ---------------------------------------------------------------------------
extern "C" void kernel_launch(void* const* d_in, const int* in_sizes, int n_in,
                              void* d_out, int out_size, void* d_ws, size_t ws_size,
                              hipStream_t stream) {
    const float* images = (const float*)d_in[0];   // [32,64,128,128]
    const float* atts   = (const float*)d_in[1];   // [32,512]
    const float* W      = (const float*)d_in[2];   // [4096,512]
    const float* b      = (const float*)d_in[3];   // [4096]
    float* out = (float*)d_out;                    // [32,64,128,128]

    // workspace: logits f32 [32*4096] (512 KB) then a_pk bf16 [32*4096] (256 KB)
    float* logits = (float*)d_ws;
    unsigned short* a_pk = (unsigned short*)(logits + NB * CC2);

    logits_kernel<<<CC2 / 2, 256, 0, stream>>>(atts, W, b, logits);
    softmax_kernel<<<NB, 512, 0, stream>>>(logits, a_pk);
    einsum_kernel<<<2048, 512, 0, stream>>>(images, a_pk, out);
}

// Round 15
// 83.149 us; speedup vs baseline: 2.1069x; 1.0733x over previous
//
#include <hip/hip_runtime.h>
#include <hip/hip_bf16.h>

// Problem constants (AttentionalPlanarRemapping): N=32, C=64, H=W=128, E=512
#define NB   32
#define CC   64
#define HW   16384          // 128*128
#define EE   512
#define CC2  4096           // C*C

using short8  = __attribute__((ext_vector_type(8))) short;
using f32x16  = __attribute__((ext_vector_type(16))) float;

// fp32 -> bf16 round-to-nearest-even
__device__ __forceinline__ unsigned short f2bf(float x) {
    unsigned int u = __float_as_uint(x);
    u += 0x7FFFu + ((u >> 16) & 1u);
    return (unsigned short)(u >> 16);
}

// ---------------------------------------------------------------------------
// Kernel 1: logits[n][j] = dot(atts[n,:], W[j,:]) + b[j]   (unchanged)
// 2048 blocks x 256 thr; W (8 MiB) read exactly once across the grid.
// ---------------------------------------------------------------------------
__global__ __launch_bounds__(256) void logits_kernel(
    const float* __restrict__ atts, const float* __restrict__ W,
    const float* __restrict__ b, float* __restrict__ logits) {
    const int t  = threadIdx.x;
    const int j  = blockIdx.x * 2 + (t & 1);
    const int n  = (t >> 1) & 31;
    const int kq = t >> 6;                 // 0..3
    const float* __restrict__ wrow = W + (size_t)j * EE + kq * 128;
    const float* __restrict__ arow = atts + (size_t)n * EE + kq * 128;
    float acc0 = 0.f, acc1 = 0.f;
    #pragma unroll
    for (int k = 0; k < 128; k += 8) {
        float4 w0 = *reinterpret_cast<const float4*>(wrow + k);
        float4 a0 = *reinterpret_cast<const float4*>(arow + k);
        float4 w1 = *reinterpret_cast<const float4*>(wrow + k + 4);
        float4 a1 = *reinterpret_cast<const float4*>(arow + k + 4);
        acc0 = fmaf(w0.x, a0.x, acc0); acc0 = fmaf(w0.y, a0.y, acc0);
        acc0 = fmaf(w0.z, a0.z, acc0); acc0 = fmaf(w0.w, a0.w, acc0);
        acc1 = fmaf(w1.x, a1.x, acc1); acc1 = fmaf(w1.y, a1.y, acc1);
        acc1 = fmaf(w1.z, a1.z, acc1); acc1 = fmaf(w1.w, a1.w, acc1);
    }
    __shared__ float part[256];
    part[t] = acc0 + acc1;
    __syncthreads();
    if (t < 64) {
        const int jj = blockIdx.x * 2 + (t & 1);
        const int nn = t >> 1;
        const float r = part[t] + part[t + 64] + part[t + 128] + part[t + 192];
        logits[(size_t)nn * CC2 + jj] = r + b[jj];
    }
}

// ---------------------------------------------------------------------------
// Kernel 2 (FUSED softmax + einsum): out[n,c,px] = sum_d a[n,c,d]*img[n,d,px]
// grid (64 px-tiles, 32 n) x 512 thr (8 waves). Per block:
//  A: issue the 8 float4 img loads (in flight through all of phase B)
//  B: recompute double-softmax of logits[n] (16 KB, L2-hot) -> aLds packed
//     in MFMA A-fragment order (identical math to R14's verified K2);
//     this VALU work hides under the img HBM latency the block otherwise
//     stalls on (R12: VALUBusy 7%).
//  C: cvt imgs -> sImg LDS; barrier
//  D: 4 k-steps x {2x ds_read_b128 A-frags, 8x ds_read_u16 B-frag,
//     2x v_mfma_f32_32x32x16_bf16}
//  E: regular strided stores (nt was proven neutral, R12 A/B).
// LDS: s 16 KB + aLds 8 KB + sImg 32 KB = 56 KB -> 2 blocks/CU (perf-neutral
// per R9's 66-KB datapoint). Eliminates K2 launch + gap + a_pk round-trip.
// ---------------------------------------------------------------------------
__global__ __launch_bounds__(512) void einsum_kernel(
    const float* __restrict__ img, const float* __restrict__ logits,
    float* __restrict__ out) {
    const int t    = threadIdx.x;
    const int lane = t & 63;
    const int wv   = t >> 6;                   // wave 0..7
    const int n    = blockIdx.y;
    const int px0  = blockIdx.x * 256;
    const int lh   = lane >> 5;                // k-group half
    const int lc   = lane & 31;

    __shared__ float s[CC2];                   // 16 KB: softmax scratch
    __shared__ unsigned short aLds[CC2];       // 8 KB: packed A fragments
    __shared__ unsigned short sImg[CC * 256];  // 32 KB: [d][px] bf16 tile
    __shared__ float wmax[8];
    __shared__ float wsum[8];

    // ---- A: issue img loads; they stay in flight through phase B ----
    const int px_l = (t & 63) * 4;             // 0..252
    const int d0   = (t >> 6) * 8;             // 0,8,..,56
    const float* __restrict__ gp = img + (size_t)n * (CC * HW) + px0 + px_l;
    float4 v0 = *reinterpret_cast<const float4*>(gp + (size_t)(d0 + 0) * HW);
    float4 v1 = *reinterpret_cast<const float4*>(gp + (size_t)(d0 + 1) * HW);
    float4 v2 = *reinterpret_cast<const float4*>(gp + (size_t)(d0 + 2) * HW);
    float4 v3 = *reinterpret_cast<const float4*>(gp + (size_t)(d0 + 3) * HW);
    float4 v4 = *reinterpret_cast<const float4*>(gp + (size_t)(d0 + 4) * HW);
    float4 v5 = *reinterpret_cast<const float4*>(gp + (size_t)(d0 + 5) * HW);
    float4 v6 = *reinterpret_cast<const float4*>(gp + (size_t)(d0 + 6) * HW);
    float4 v7 = *reinterpret_cast<const float4*>(gp + (size_t)(d0 + 7) * HW);

    // ---- B: double softmax of logits[n] (identical math to verified K2) ----
    {
        const float* __restrict__ L = logits + (size_t)n * CC2;
        float l[8];
        float lmax = -1e30f;
        #pragma unroll
        for (int i = 0; i < 8; ++i) {
            l[i] = L[t + i * 512];
            lmax = fmaxf(lmax, l[i]);
        }
        #pragma unroll
        for (int off = 32; off > 0; off >>= 1) lmax = fmaxf(lmax, __shfl_xor(lmax, off));
        if ((t & 63) == 0) wmax[t >> 6] = lmax;
        __syncthreads();
        float bmax = wmax[0];
        #pragma unroll
        for (int i = 1; i < 8; ++i) bmax = fmaxf(bmax, wmax[i]);

        float lsum = 0.f;
        #pragma unroll
        for (int i = 0; i < 8; ++i) {
            float e = __expf(l[i] - bmax);
            s[t + i * 512] = e;
            lsum += e;
        }
        #pragma unroll
        for (int off = 32; off > 0; off >>= 1) lsum += __shfl_xor(lsum, off);
        if ((t & 63) == 0) wsum[t >> 6] = lsum;
        __syncthreads();                       // s[] + wsum visible
        float bsum = wsum[0];
        #pragma unroll
        for (int i = 1; i < 8; ++i) bsum += wsum[i];
        const float inv = 1.f / bsum;

        // softmax-2: 8 threads per row c, 8 d's each
        const int c  = t >> 3;                 // 0..63
        const int q8 = (t & 7) * 8;            // 0,8,..,56
        const float* __restrict__ row = s + c * CC + q8;
        float vv[8];
        #pragma unroll
        for (int i = 0; i < 8; ++i) vv[i] = row[i] * inv;
        float mx = vv[0];
        #pragma unroll
        for (int i = 1; i < 8; ++i) mx = fmaxf(mx, vv[i]);
        mx = fmaxf(mx, __shfl_xor(mx, 1));
        mx = fmaxf(mx, __shfl_xor(mx, 2));
        mx = fmaxf(mx, __shfl_xor(mx, 4));
        float sum = 0.f;
        #pragma unroll
        for (int i = 0; i < 8; ++i) sum += __expf(vv[i] - mx);
        sum += __shfl_xor(sum, 1);
        sum += __shfl_xor(sum, 2);
        sum += __shfl_xor(sum, 4);
        const float isum = 1.f / sum;

        union { uint4 u; unsigned short h[8]; } pk;
        #pragma unroll
        for (int i = 0; i < 8; ++i) pk.h[i] = f2bf(__expf(vv[i] - mx) * isum);

        const int ks   = q8 >> 4;
        const int lhp  = (q8 >> 3) & 1;
        const int half = c >> 5;
        *reinterpret_cast<uint4*>(
            &aLds[(size_t)(ks * 2 + half) * 512 + (lhp * 32 + (c & 31)) * 8]) = pk.u;
    }

    // ---- C: cvt staged img regs -> sImg ----
    {
        union { uint2 u; unsigned short h[4]; } pk;
        #define STG(i, vv) \
            pk.h[0] = f2bf(vv.x); pk.h[1] = f2bf(vv.y); \
            pk.h[2] = f2bf(vv.z); pk.h[3] = f2bf(vv.w); \
            *reinterpret_cast<uint2*>(&sImg[(d0 + i) * 256 + px_l]) = pk.u;
        STG(0, v0) STG(1, v1) STG(2, v2) STG(3, v3)
        STG(4, v4) STG(5, v5) STG(6, v6) STG(7, v7)
        #undef STG
    }
    __syncthreads();   // orders aLds + sImg writes before phase D reads

    // ---- D: MFMA compute ----
    const int px_w = wv * 32 + lc;
    f32x16 acc0 = {};   // c = 0..31
    f32x16 acc1 = {};   // c = 32..63

    #pragma unroll
    for (int ks = 0; ks < 4; ++ks) {
        const int kbase = ks * 16 + lh * 8;
        union { short8 v; unsigned short h[8]; } bf;
        #pragma unroll
        for (int e = 0; e < 8; ++e)
            bf.h[e] = sImg[(kbase + e) * 256 + px_w];
        short8 a0 = *reinterpret_cast<const short8*>(&aLds[(ks * 2 + 0) * 512 + lane * 8]);
        short8 a1 = *reinterpret_cast<const short8*>(&aLds[(ks * 2 + 1) * 512 + lane * 8]);
        acc0 = __builtin_amdgcn_mfma_f32_32x32x16_bf16(a0, bf.v, acc0, 0, 0, 0);
        acc1 = __builtin_amdgcn_mfma_f32_32x32x16_bf16(a1, bf.v, acc1, 0, 0, 0);
    }

    // ---- E: stores ----
    float* __restrict__ op = out + (size_t)n * (CC * HW) + px0 + px_w;
    #pragma unroll
    for (int r = 0; r < 16; ++r) {
        const int row = (r & 3) + 8 * (r >> 2) + 4 * lh;
        op[(size_t)row * HW]        = acc0[r];
        op[(size_t)(row + 32) * HW] = acc1[r];
    }
}

// ---------------------------------------------------------------------------
extern "C" void kernel_launch(void* const* d_in, const int* in_sizes, int n_in,
                              void* d_out, int out_size, void* d_ws, size_t ws_size,
                              hipStream_t stream) {
    const float* images = (const float*)d_in[0];   // [32,64,128,128]
    const float* atts   = (const float*)d_in[1];   // [32,512]
    const float* W      = (const float*)d_in[2];   // [4096,512]
    const float* b      = (const float*)d_in[3];   // [4096]
    float* out = (float*)d_out;                    // [32,64,128,128]

    // workspace: logits f32 [32*4096] (512 KB)
    float* logits = (float*)d_ws;

    logits_kernel<<<CC2 / 2, 256, 0, stream>>>(atts, W, b, logits);
    einsum_kernel<<<dim3(HW / 256, NB), 512, 0, stream>>>(images, logits, out);
}